// Round 5
// baseline (285.007 us; speedup 1.0000x reference)
//
#include <hip/hip_runtime.h>
#include <math.h>

#define EPSV 1e-5f

typedef __attribute__((ext_vector_type(8))) short short8;
typedef __attribute__((ext_vector_type(4))) float f32x4;

// pack two f32 -> two bf16 (RTNE) in one uint
static __device__ __forceinline__ unsigned bfpack2(float lo, float hi) {
    union { float f; unsigned u; } a, b;
    a.f = lo; b.f = hi;
    unsigned ua = a.u + 0x7fffu + ((a.u >> 16) & 1u);
    unsigned ub = b.u + 0x7fffu + ((b.u >> 16) & 1u);
    return (ua >> 16) | (ub & 0xffff0000u);
}
static __device__ __forceinline__ unsigned short bf1(float v) {
    return (unsigned short)bfpack2(v, 0.f);
}
static __device__ __forceinline__ float b2f(unsigned short u) {
    union { unsigned u; float f; } x; x.u = ((unsigned)u) << 16; return x.f;
}

// ---------------------------------------------------------------------------
// K1 gram: G[b] = X_b^T X_b (bf16 out), symmetric 3-tile scheme, 512 thr,
// XOR-swizzled LDS staging, register double-buffer prefetch (chunk kc+1's
// global loads issue before chunk kc's MFMAs; 512-thr blocks are 1/CU, so
// the extra VGPRs cost no occupancy).
// Grid 384: id = (tile*2+path)*64 + b  (b=id&63 -> XCD affinity).
// ---------------------------------------------------------------------------
__global__ __launch_bounds__(512) void gram(
    const float* __restrict__ Xx, const float* __restrict__ Xz,
    unsigned short* __restrict__ Gx, unsigned short* __restrict__ Gz,
    float* __restrict__ csx, float* __restrict__ csz)
{
    __shared__ __align__(16) unsigned short AT[128 * 72];
    __shared__ __align__(16) unsigned short BT[128 * 72];
    __shared__ float csr[16 * 128];
    const int id = blockIdx.x;
    const int b = id & 63;
    const int path = (id >> 6) & 1;
    const int tile = id >> 7;            // 0,1: diag; 2: off-diag
    const bool diag = (tile < 2);
    const int ci = diag ? tile : 0;
    const float* X = path ? Xz : Xx;
    unsigned short* G = (path ? Gz : Gx) + (long)b * 65536;
    float* cs = path ? csz : csx;
    const int P = path ? 256 : 1024;
    const int nk = P >> 6;
    const int t = threadIdx.x;
    const int cq = (t & 31) * 4;         // col base within 128-group
    const int ph = t >> 5;               // 0..15, 4 p each
    const int w = t >> 6;                // wave 0..7
    const int quad = (t >> 4) & 3, lane16 = t & 15;
    const float* Xb = X + (long)b * P * 256;
    const int colA = ci * 128;

    f32x4 acc[4][4] = {};
    float csA[4] = {0.f, 0.f, 0.f, 0.f};

    float4 va[4], vb[4];
    {
        const int p0 = ph * 4;
#pragma unroll
        for (int k = 0; k < 4; ++k)
            va[k] = *(const float4*)(Xb + (long)(p0 + k) * 256 + colA + cq);
        if (!diag) {
#pragma unroll
            for (int k = 0; k < 4; ++k)
                vb[k] = *(const float4*)(Xb + (long)(p0 + k) * 256 + 128 + cq);
        }
    }

    for (int kc = 0; kc < nk; ++kc) {
        __syncthreads();   // previous chunk's MFMA reads done
#pragma unroll
        for (int j = 0; j < 4; ++j) {
            const int row = cq + j;
            const int key = (row >> 2) & 7;
            uint2 pk;
            pk.x = bfpack2(((const float*)&va[0])[j], ((const float*)&va[1])[j]);
            pk.y = bfpack2(((const float*)&va[2])[j], ((const float*)&va[3])[j]);
            *(uint2*)&AT[row * 72 + (((ph >> 1) ^ key) << 3) + ((ph & 1) << 2)] = pk;
            if (diag)
                csA[j] += ((const float*)&va[0])[j] + ((const float*)&va[1])[j]
                        + ((const float*)&va[2])[j] + ((const float*)&va[3])[j];
        }
        if (!diag) {
#pragma unroll
            for (int j = 0; j < 4; ++j) {
                const int row = cq + j;
                const int key = (row >> 2) & 7;
                uint2 pk;
                pk.x = bfpack2(((const float*)&vb[0])[j], ((const float*)&vb[1])[j]);
                pk.y = bfpack2(((const float*)&vb[2])[j], ((const float*)&vb[3])[j]);
                *(uint2*)&BT[row * 72 + (((ph >> 1) ^ key) << 3) + ((ph & 1) << 2)] = pk;
            }
        }
        __syncthreads();
        // prefetch next chunk (overlaps MFMA phase below)
        float4 nva[4], nvb[4];
        if (kc + 1 < nk) {
            const int p0 = (kc + 1) * 64 + ph * 4;
#pragma unroll
            for (int k = 0; k < 4; ++k)
                nva[k] = *(const float4*)(Xb + (long)(p0 + k) * 256 + colA + cq);
            if (!diag) {
#pragma unroll
                for (int k = 0; k < 4; ++k)
                    nvb[k] = *(const float4*)(Xb + (long)(p0 + k) * 256 + 128 + cq);
            }
        }
        if (diag) {
            const int wr = w >> 2, wc4 = w & 3;   // 2x4 grid of 64x32 subtiles
#pragma unroll
            for (int ks = 0; ks < 2; ++ks) {
                const int slot = ks * 4 + quad;
                short8 bfr[2];
#pragma unroll
                for (int ni = 0; ni < 2; ++ni) {
                    const int rw = wc4 * 32 + ni * 16 + lane16;
                    bfr[ni] = *(const short8*)&AT[rw * 72 + ((slot ^ ((rw >> 2) & 7)) << 3)];
                }
#pragma unroll
                for (int mi = 0; mi < 4; ++mi) {
                    const int ra = wr * 64 + mi * 16 + lane16;
                    short8 afr = *(const short8*)&AT[ra * 72 + ((slot ^ ((ra >> 2) & 7)) << 3)];
#pragma unroll
                    for (int ni = 0; ni < 2; ++ni)
                        acc[mi][ni] = __builtin_amdgcn_mfma_f32_16x16x32_bf16(afr, bfr[ni], acc[mi][ni], 0, 0, 0);
                }
            }
        } else {
            const int sel = w >> 2, w2 = w & 3, wr = w2 >> 1, wc = w2 & 1;
            const unsigned short* As = sel ? BT : AT;
            const unsigned short* Bs = sel ? AT : BT;
#pragma unroll
            for (int ks = 0; ks < 2; ++ks) {
                const int slot = ks * 4 + quad;
                short8 bfr[4];
#pragma unroll
                for (int ni = 0; ni < 4; ++ni) {
                    const int rw = wc * 64 + ni * 16 + lane16;
                    bfr[ni] = *(const short8*)&Bs[rw * 72 + ((slot ^ ((rw >> 2) & 7)) << 3)];
                }
#pragma unroll
                for (int mi = 0; mi < 4; ++mi) {
                    const int ra = wr * 64 + mi * 16 + lane16;
                    short8 afr = *(const short8*)&As[ra * 72 + ((slot ^ ((ra >> 2) & 7)) << 3)];
#pragma unroll
                    for (int ni = 0; ni < 4; ++ni)
                        acc[mi][ni] = __builtin_amdgcn_mfma_f32_16x16x32_bf16(afr, bfr[ni], acc[mi][ni], 0, 0, 0);
                }
            }
        }
#pragma unroll
        for (int k = 0; k < 4; ++k) { va[k] = nva[k]; vb[k] = nvb[k]; }
    }
    if (diag) {
        const int wr = w >> 2, wc4 = w & 3;
#pragma unroll
        for (int mi = 0; mi < 4; ++mi) {
            const int rbase = ci * 128 + wr * 64 + mi * 16 + quad * 4;
#pragma unroll
            for (int ni = 0; ni < 2; ++ni) {
                const int col = ci * 128 + wc4 * 32 + ni * 16 + lane16;
#pragma unroll
                for (int r = 0; r < 4; ++r)
                    G[(rbase + r) * 256 + col] = bf1(acc[mi][ni][r]);
            }
        }
#pragma unroll
        for (int j = 0; j < 4; ++j) csr[ph * 128 + cq + j] = csA[j];
        __syncthreads();
        if (t < 128) {
            float s = 0.f;
#pragma unroll
            for (int k = 0; k < 16; ++k) s += csr[k * 128 + t];
            cs[b * 256 + ci * 128 + t] = s;
        }
    } else {
        const int sel = w >> 2, w2 = w & 3, wr = w2 >> 1, wc = w2 & 1;
        const int R = sel ? 128 : 0, C = sel ? 0 : 128;
#pragma unroll
        for (int mi = 0; mi < 4; ++mi) {
            const int rbase = R + wr * 64 + mi * 16 + quad * 4;
#pragma unroll
            for (int ni = 0; ni < 4; ++ni) {
                const int col = C + wc * 64 + ni * 16 + lane16;
#pragma unroll
                for (int r = 0; r < 4; ++r)
                    G[(rbase + r) * 256 + col] = bf1(acc[mi][ni][r]);
            }
        }
    }
}

// ---------------------------------------------------------------------------
// K2 projz: kern slice = Wz^T Gz + bz(x)csz (LDS only) -> dy partials.
// Grid 256: b=id&63, ct=id>>6. B-fragments read directly from bf16 Gz (L2).
// ---------------------------------------------------------------------------
__global__ __launch_bounds__(256) void projz(
    const unsigned short* __restrict__ Gz, const float* __restrict__ csz,
    const float* __restrict__ Wz, const float* __restrict__ bz,
    const float* __restrict__ Wdyn, float* __restrict__ dypart)
{
    __shared__ __align__(16) unsigned short ATW[64 * 264];
    __shared__ float SLICE[64 * 68];
    __shared__ float WC2[64 * 68];
    __shared__ float WD3L[192];
    const int t = threadIdx.x;
    const int id = blockIdx.x;
    const int b = id & 63, ct = id >> 6;
    const int n = t & 63, ph2 = t >> 6;
#pragma unroll
    for (int cc = 0; cc < 4; ++cc) {
        float v[16];
#pragma unroll
        for (int k = 0; k < 16; ++k) v[k] = Wz[(ph2 * 64 + cc * 16 + k) * 64 + n];
        uint4 p0, p1;
        p0.x = bfpack2(v[0], v[1]);   p0.y = bfpack2(v[2], v[3]);
        p0.z = bfpack2(v[4], v[5]);   p0.w = bfpack2(v[6], v[7]);
        p1.x = bfpack2(v[8], v[9]);   p1.y = bfpack2(v[10], v[11]);
        p1.z = bfpack2(v[12], v[13]); p1.w = bfpack2(v[14], v[15]);
        *(uint4*)&ATW[n * 264 + ph2 * 64 + cc * 16]     = p0;
        *(uint4*)&ATW[n * 264 + ph2 * 64 + cc * 16 + 8] = p1;
    }
    __syncthreads();
    const int w = t >> 6, quad = (t >> 4) & 3, lane16 = t & 15;
    const unsigned short* Grow =
        Gz + (long)(b * 256 + ct * 64 + w * 16 + lane16) * 256 + quad * 8;
    short8 bfr[8];
#pragma unroll
    for (int u = 0; u < 8; ++u) bfr[u] = *(const short8*)(Grow + u * 32);
    f32x4 acc[4] = {{0.f,0.f,0.f,0.f},{0.f,0.f,0.f,0.f},{0.f,0.f,0.f,0.f},{0.f,0.f,0.f,0.f}};
#pragma unroll
    for (int kc = 0; kc < 4; ++kc)
#pragma unroll
        for (int ks = 0; ks < 2; ++ks) {
            const int ko = ks * 32 + quad * 8;
            const short8 bfrag = bfr[kc * 2 + ks];
#pragma unroll
            for (int mi = 0; mi < 4; ++mi) {
                short8 afrag = *(const short8*)&ATW[(mi * 16 + lane16) * 264 + kc * 64 + ko];
                acc[mi] = __builtin_amdgcn_mfma_f32_16x16x32_bf16(afrag, bfrag, acc[mi], 0, 0, 0);
            }
        }
    const int col = ct * 64 + w * 16 + lane16;
    const float csv = csz[b * 256 + col];
    const int cloc = w * 16 + lane16;
#pragma unroll
    for (int mi = 0; mi < 4; ++mi) {
        const int nrow = mi * 16 + quad * 4;
#pragma unroll
        for (int r = 0; r < 4; ++r)
            SLICE[cloc * 68 + nrow + r] = acc[mi][r] + bz[nrow + r] * csv;
    }
    {
        const int m = t & 63, clg = t >> 6;
#pragma unroll
        for (int j = 0; j < 16; ++j) {
            const int cl = clg * 16 + j;
            WC2[cl * 68 + m] = Wdyn[((long)(ct * 64 + cl)) * 67 + 3 + m];
        }
        if (t < 192) WD3L[t] = Wdyn[((long)(ct * 64 + t / 3)) * 67 + (t % 3)];
    }
    __syncthreads();
    const int tr = t >> 4, tc = t & 15;
    float adv[4][4] = {};
#pragma unroll 16
    for (int cl = 0; cl < 64; ++cl) {
        float4 a  = *(float4*)&SLICE[cl * 68 + tr * 4];
        float4 wv = *(float4*)&WC2[cl * 68 + tc * 4];
        adv[0][0]+=a.x*wv.x; adv[0][1]+=a.x*wv.y; adv[0][2]+=a.x*wv.z; adv[0][3]+=a.x*wv.w;
        adv[1][0]+=a.y*wv.x; adv[1][1]+=a.y*wv.y; adv[1][2]+=a.y*wv.z; adv[1][3]+=a.y*wv.w;
        adv[2][0]+=a.z*wv.x; adv[2][1]+=a.z*wv.y; adv[2][2]+=a.z*wv.z; adv[2][3]+=a.z*wv.w;
        adv[3][0]+=a.w*wv.x; adv[3][1]+=a.w*wv.y; adv[3][2]+=a.w*wv.z; adv[3][3]+=a.w*wv.w;
    }
    const long base = (long)(b * 4 + ct) * 64;
#pragma unroll
    for (int i = 0; i < 4; ++i) {
        float4 o = make_float4(adv[i][0], adv[i][1], adv[i][2], adv[i][3]);
        *(float4*)(dypart + (base + tr * 4 + i) * 68 + tc * 4) = o;
    }
    if (t < 192) {
        const int nwd3 = t / 3, jwd3 = t - nwd3 * 3;
        float wdacc = 0.f;
#pragma unroll 16
        for (int cl = 0; cl < 64; ++cl)
            wdacc += SLICE[cl * 68 + nwd3] * WD3L[cl * 3 + jwd3];
        dypart[(base + nwd3) * 68 + 64 + jwd3] = wdacc;
    }
}

// ---------------------------------------------------------------------------
// K3 dpx: proj-x (MFMA from Gx) computed straight into LDS (vt) + halo cols
// via bf16 VALU dot, then depth conv + point GEMM. kxr global eliminated.
// grid (4, 64), 256 thr. LDS union: ATW (MFMA phase) -> vt+dep (conv phase).
// ---------------------------------------------------------------------------
__global__ __launch_bounds__(256) void dpx(
    const unsigned short* __restrict__ Gx, const float* __restrict__ csx,
    const float* __restrict__ Wx, const float* __restrict__ bx,
    const float* __restrict__ dyp, const float* __restrict__ bdyn,
    const float* __restrict__ g, const float* __restrict__ Wp,
    float* __restrict__ point, float* __restrict__ partials)
{
    __shared__ __align__(16) unsigned char pool[53248];
    unsigned short* ATW = (unsigned short*)pool;          // [64][264] ush, phase 1
    float* vt  = (float*)pool;                            // [64][68] f32, phase 2 (aliases ATW)
    float* dep = (float*)(pool + 17408);                  // [64][68]
    float* wpT = (float*)(pool + 34816);                  // [64][68]
    float* wd3 = (float*)(pool + 52224);                  // [64][4]
    float* rs  = vt;                                      // [3*1088] aliases vt (dead after conv)

    const int t = threadIdx.x;
    const int b = blockIdx.y, ct = blockIdx.x, c0 = ct * 64;
    const int tr = t >> 4, tc = t & 15;
    const int w = t >> 6, quad = (t >> 4) & 3, lane16 = t & 15;

    // ---- stage wpT/wd3 (dy partials reduce + bias) and ATW (Wx^T bf16) ----
#pragma unroll
    for (int i = 0; i < 4; ++i) {
        int idx = t + i * 256; int n = idx >> 4, m0 = (idx & 15) * 4;
        float4 a0 = *(const float4*)(dyp + ((long)((b * 4 + 0) * 64 + n)) * 68 + m0);
        float4 a1 = *(const float4*)(dyp + ((long)((b * 4 + 1) * 64 + n)) * 68 + m0);
        float4 a2 = *(const float4*)(dyp + ((long)((b * 4 + 2) * 64 + n)) * 68 + m0);
        float4 a3 = *(const float4*)(dyp + ((long)((b * 4 + 3) * 64 + n)) * 68 + m0);
        float4 w4;
        w4.x = a0.x + a1.x + a2.x + a3.x + bdyn[3 + m0 + 0];
        w4.y = a0.y + a1.y + a2.y + a3.y + bdyn[3 + m0 + 1];
        w4.z = a0.z + a1.z + a2.z + a3.z + bdyn[3 + m0 + 2];
        w4.w = a0.w + a1.w + a2.w + a3.w + bdyn[3 + m0 + 3];
        wpT[(m0+0)*68 + n] = w4.x; wpT[(m0+1)*68 + n] = w4.y;
        wpT[(m0+2)*68 + n] = w4.z; wpT[(m0+3)*68 + n] = w4.w;
    }
    if (t < 64) {
        long o0 = ((long)((b * 4 + 0) * 64 + t)) * 68 + 64;
        long o1 = ((long)((b * 4 + 1) * 64 + t)) * 68 + 64;
        long o2 = ((long)((b * 4 + 2) * 64 + t)) * 68 + 64;
        long o3 = ((long)((b * 4 + 3) * 64 + t)) * 68 + 64;
#pragma unroll
        for (int j = 0; j < 3; ++j)
            wd3[t*4+j] = dyp[o0+j] + dyp[o1+j] + dyp[o2+j] + dyp[o3+j] + bdyn[j];
    }
    {
        const int n = t & 63, ph2 = t >> 6;
#pragma unroll
        for (int cc = 0; cc < 4; ++cc) {
            float v[16];
#pragma unroll
            for (int k = 0; k < 16; ++k) v[k] = Wx[(ph2 * 64 + cc * 16 + k) * 64 + n];
            uint4 p0, p1;
            p0.x = bfpack2(v[0], v[1]);   p0.y = bfpack2(v[2], v[3]);
            p0.z = bfpack2(v[4], v[5]);   p0.w = bfpack2(v[6], v[7]);
            p1.x = bfpack2(v[8], v[9]);   p1.y = bfpack2(v[10], v[11]);
            p1.z = bfpack2(v[12], v[13]); p1.w = bfpack2(v[14], v[15]);
            *(uint4*)&ATW[n * 264 + ph2 * 64 + cc * 16]     = p0;
            *(uint4*)&ATW[n * 264 + ph2 * 64 + cc * 16 + 8] = p1;
        }
    }
    __syncthreads();
    // ---- proj-x MFMA: out[n][c] for the ct tile ----
    const unsigned short* Grow =
        Gx + (long)(b * 256 + c0 + w * 16 + lane16) * 256 + quad * 8;
    short8 bfr[8];
#pragma unroll
    for (int u = 0; u < 8; ++u) bfr[u] = *(const short8*)(Grow + u * 32);
    f32x4 pacc[4] = {{0.f,0.f,0.f,0.f},{0.f,0.f,0.f,0.f},{0.f,0.f,0.f,0.f},{0.f,0.f,0.f,0.f}};
#pragma unroll
    for (int kc = 0; kc < 4; ++kc)
#pragma unroll
        for (int ks = 0; ks < 2; ++ks) {
            const int ko = ks * 32 + quad * 8;
            const short8 bfrag = bfr[kc * 2 + ks];
#pragma unroll
            for (int mi = 0; mi < 4; ++mi) {
                short8 afrag = *(const short8*)&ATW[(mi * 16 + lane16) * 264 + kc * 64 + ko];
                pacc[mi] = __builtin_amdgcn_mfma_f32_16x16x32_bf16(afrag, bfrag, pacc[mi], 0, 0, 0);
            }
        }
    // ---- halo columns (c0-1, c0+64) via bf16 VALU dot ----
    float edgeval = 0.f;
    if (t < 128) {
        const int n = t & 63, e = t >> 6;
        const int colg = e ? (c0 + 64) : (c0 - 1);
        if (colg >= 0 && colg < 256) {
            const unsigned short* gr = Gx + ((long)(b * 256 + colg)) * 256;
            float accd = 0.f;
#pragma unroll 8
            for (int k = 0; k < 256; k += 8) {
                short8 gs = *(const short8*)(gr + k);
                short8 wsv = *(const short8*)&ATW[n * 264 + k];
#pragma unroll
                for (int j = 0; j < 8; ++j)
                    accd += b2f((unsigned short)gs[j]) * b2f((unsigned short)wsv[j]);
            }
            edgeval = accd + bx[n] * csx[b * 256 + colg];
        }
    }
    __syncthreads();   // ATW dead; vt region live
    // ---- write vt (kxr tile + halos) ----
    {
        const float csv = csx[b * 256 + c0 + w * 16 + lane16];
        const int lc = 1 + w * 16 + lane16;
#pragma unroll
        for (int mi = 0; mi < 4; ++mi) {
            const int nrow = mi * 16 + quad * 4;
#pragma unroll
            for (int r = 0; r < 4; ++r)
                vt[(nrow + r) * 68 + lc] = pacc[mi][r] + bx[nrow + r] * csv;
        }
    }
    if (t < 128) {
        const int n = t & 63, e = t >> 6;
        vt[n * 68 + (e ? 65 : 0)] = edgeval;
    }
    __syncthreads();
    // ---- depth conv ----
#pragma unroll
    for (int im = 0; im < 4; ++im) {
        int m = tr * 4 + im;
        float w0 = wd3[m*4+0], w1 = wd3[m*4+1], w2 = wd3[m*4+2];
#pragma unroll
        for (int jc = 0; jc < 4; ++jc) {
            int cl = tc * 4 + jc;
            float d = w0 * vt[m*68 + cl] + w1 * vt[m*68 + cl + 1] + w2 * vt[m*68 + cl + 2];
            dep[m*68 + cl] = fmaxf(d, 0.f);
        }
    }
    __syncthreads();
    // ---- point GEMM ----
    float acc[4][4] = {};
#pragma unroll 16
    for (int m = 0; m < 64; ++m) {
        float4 a4 = *(float4*)&wpT[m * 68 + tr * 4];
        float4 d4 = *(float4*)&dep[m * 68 + tc * 4];
        acc[0][0]+=a4.x*d4.x; acc[0][1]+=a4.x*d4.y; acc[0][2]+=a4.x*d4.z; acc[0][3]+=a4.x*d4.w;
        acc[1][0]+=a4.y*d4.x; acc[1][1]+=a4.y*d4.y; acc[1][2]+=a4.y*d4.z; acc[1][3]+=a4.y*d4.w;
        acc[2][0]+=a4.z*d4.x; acc[2][1]+=a4.z*d4.y; acc[2][2]+=a4.z*d4.z; acc[2][3]+=a4.z*d4.w;
        acc[3][0]+=a4.w*d4.x; acc[3][1]+=a4.w*d4.y; acc[3][2]+=a4.w*d4.z; acc[3][3]+=a4.w*d4.w;
    }
    int cg = c0 + tc * 4;
    float4 g4  = *(const float4*)(g + cg);
    float4 wp4 = *(const float4*)(Wp + cg);
    float gw0 = g4.x*wp4.x, gw1 = g4.y*wp4.y, gw2 = g4.z*wp4.z, gw3 = g4.w*wp4.w;
#pragma unroll
    for (int i = 0; i < 4; ++i) {
        float4 o = make_float4(acc[i][0], acc[i][1], acc[i][2], acc[i][3]);
        *(float4*)(point + ((long)(b * 64 + tr * 4 + i)) * 256 + cg) = o;
        float s  = o.x + o.y + o.z + o.w;
        float s2 = o.x*o.x + o.y*o.y + o.z*o.z + o.w*o.w;
        float dg = o.x*gw0 + o.y*gw1 + o.z*gw2 + o.w*gw3;
        rs[0*1088 + (tr*4+i)*17 + tc] = s;
        rs[1*1088 + (tr*4+i)*17 + tc] = s2;
        rs[2*1088 + (tr*4+i)*17 + tc] = dg;
    }
    __syncthreads();
    if (t < 64) {
        float s = 0.f, s2 = 0.f, dg = 0.f;
#pragma unroll
        for (int j = 0; j < 16; ++j) {
            s  += rs[t*17 + j];
            s2 += rs[1088 + t*17 + j];
            dg += rs[2176 + t*17 + j];
        }
        long base = ((long)(b * 4 + ct)) * 192;
        partials[base + t]        = s;
        partials[base + 64 + t]   = s2;
        partials[base + 128 + t]  = dg;
    }
}

// ---------------------------------------------------------------------------
// K4 lnbuild: lntem (redundant per mt tile, identical arithmetic) + buildM.
// Grid 256: b=id&63, mt=id>>6. murr/AB globals eliminated (LDS only).
// ---------------------------------------------------------------------------
__global__ __launch_bounds__(256) void lnbuild(
    const float* __restrict__ partials, const float* __restrict__ point,
    const float* __restrict__ g, const float* __restrict__ bta,
    const float* __restrict__ Wp, const float* __restrict__ bp,
    const float* __restrict__ Wx, const float* __restrict__ bx,
    unsigned short* __restrict__ MT, float* __restrict__ svec)
{
    __shared__ float sA[256], sB[256];
    __shared__ float wnv[64];
    __shared__ float tot[4];
    __shared__ float MURR[128];
    __shared__ float ABL[512];
    __shared__ float ks_s[64 * 68];
    __shared__ float wt_s[64 * 68];
    const int id = blockIdx.x;
    const int b = id & 63, mt = id >> 6;
    const int t = threadIdx.x;
    // ---- lntem ----
    {
        const int c = t;
        float gc = g[c], bc = bta[c], wpc = Wp[c];
        sA[t] = gc * wpc; sB[t] = bc * wpc;
        __syncthreads();
        for (int off = 128; off >= 1; off >>= 1) {
            if (t < off) { sA[t] += sA[t+off]; sB[t] += sB[t+off]; }
            __syncthreads();
        }
        if (t == 0) { tot[0] = sA[0]; tot[1] = sB[0] + bp[0]; }
        __syncthreads();
        float Sgw = tot[0], Sbw = tot[1];

        float protoe = 0.f, mu = 0.f, rr = 0.f;
        if (t < 64) {
            float S1 = 0.f, S2 = 0.f, Sdg = 0.f;
#pragma unroll
            for (int ct = 0; ct < 4; ++ct) {
                long o = ((long)(b * 4 + ct)) * 192;
                S1 += partials[o + t]; S2 += partials[o + 64 + t]; Sdg += partials[o + 128 + t];
            }
            mu = S1 * (1.f / 256.f);
            float var = S2 * (1.f / 256.f) - mu * mu;
            rr = rsqrtf(var + EPSV);
            protoe = rr * (Sdg - mu * Sgw) + Sbw;
            wnv[t] = protoe * rr;
            MURR[2*t] = rr; MURR[2*t + 1] = -mu * rr;
        }
        __syncthreads();
        sA[t] = (t < 64) ? protoe * rr * mu : 0.f;
        sB[t] = (t < 64) ? protoe : 0.f;
        __syncthreads();
        for (int off = 128; off >= 1; off >>= 1) {
            if (t < off) { sA[t] += sA[t+off]; sB[t] += sB[t+off]; }
            __syncthreads();
        }
        if (t == 0) { tot[2] = sA[0]; tot[3] = sB[0]; }
        __syncthreads();
        float Bv = tot[2], Sv = tot[3];

        const float* pcol = point + (long)b * 64 * 256 + c;
        float a0 = 0.f, a1 = 0.f, a2 = 0.f, a3 = 0.f;
#pragma unroll
        for (int n = 0; n < 64; n += 4) {
            a0 += wnv[n+0] * pcol[(n+0) * 256];
            a1 += wnv[n+1] * pcol[(n+1) * 256];
            a2 += wnv[n+2] * pcol[(n+2) * 256];
            a3 += wnv[n+3] * pcol[(n+3) * 256];
        }
        float accA = a0 + a1 + a2 + a3;
        float x = gc * (accA - Bv) + bc * Sv;
        float temv = 1.f / (1.f + expf(-x));
        ABL[c] = gc * temv; ABL[256 + c] = bc * temv;
    }
    __syncthreads();
    // ---- buildM (this mt tile) ----
    {
        const int n = t >> 2, q = t & 3;
        const float rn = MURR[2 * n], qn = MURR[2 * n + 1];
        const float* prow = point + ((long)(b * 64 + n)) * 256 + mt * 64 + q * 16;
#pragma unroll
        for (int j = 0; j < 4; ++j) {
            float4 p4 = *(const float4*)(prow + j * 4);
            float4 A4 = *(float4*)&ABL[mt * 64 + q * 16 + j * 4];
            float4 B4 = *(float4*)&ABL[256 + mt * 64 + q * 16 + j * 4];
            float4 kv;
            kv.x = (p4.x * rn + qn) * A4.x + B4.x;
            kv.y = (p4.y * rn + qn) * A4.y + B4.y;
            kv.z = (p4.z * rn + qn) * A4.z + B4.z;
            kv.w = (p4.w * rn + qn) * A4.w + B4.w;
            *(float4*)&ks_s[n * 68 + q * 16 + j * 4] = kv;
        }
    }
    __syncthreads();
    if (t < 64) {
        float sv = 0.f;
#pragma unroll
        for (int n2 = 0; n2 < 64; ++n2) sv += bx[n2] * ks_s[n2 * 68 + t];
        svec[b * 256 + mt * 64 + t] = sv;
    }
    const int tr = t >> 4, tc = t & 15;
    const int nw = t & 63, ph = t >> 6;
    for (int cc = 0; cc < 4; ++cc) {
        float wv[16];
#pragma unroll
        for (int k = 0; k < 16; ++k) wv[k] = Wx[(cc * 64 + ph * 16 + k) * 64 + nw];
        __syncthreads();
#pragma unroll
        for (int k = 0; k < 16; ++k) wt_s[nw * 68 + ph * 16 + k] = wv[k];
        __syncthreads();
        float a2[4][4] = {};
#pragma unroll 16
        for (int n2 = 0; n2 < 64; ++n2) {
            float4 a4 = *(float4*)&ks_s[n2 * 68 + tr * 4];
            float4 w4 = *(float4*)&wt_s[n2 * 68 + tc * 4];
            a2[0][0]+=a4.x*w4.x; a2[0][1]+=a4.x*w4.y; a2[0][2]+=a4.x*w4.z; a2[0][3]+=a4.x*w4.w;
            a2[1][0]+=a4.y*w4.x; a2[1][1]+=a4.y*w4.y; a2[1][2]+=a4.y*w4.z; a2[1][3]+=a4.y*w4.w;
            a2[2][0]+=a4.z*w4.x; a2[2][1]+=a4.z*w4.y; a2[2][2]+=a4.z*w4.z; a2[2][3]+=a4.z*w4.w;
            a2[3][0]+=a4.w*w4.x; a2[3][1]+=a4.w*w4.y; a2[3][2]+=a4.w*w4.z; a2[3][3]+=a4.w*w4.w;
        }
#pragma unroll
        for (int i = 0; i < 4; ++i) {
            uint2 pk;
            pk.x = bfpack2(a2[i][0], a2[i][1]);
            pk.y = bfpack2(a2[i][2], a2[i][3]);
            *(uint2*)&MT[((long)(b * 256 + mt * 64 + tr * 4 + i)) * 256 + cc * 64 + tc * 4] = pk;
        }
    }
}

// ---------------------------------------------------------------------------
// K5 final3: x_corr = X_b @ M + svec via bf16 MFMA, row LN + relu + residual.
// 16-row tiles -> grid 4096 (2x memory streams/CU), slim epilogue: shuffle
// reduce + 1 barrier + direct scalar stores (no LDS scatter round-trip).
// b = id&63 (XCD affinity for MT_b).
// ---------------------------------------------------------------------------
__global__ __launch_bounds__(256) void final3(
    const float* __restrict__ xf, const unsigned short* __restrict__ MT,
    const float* __restrict__ svec, const float* __restrict__ g,
    const float* __restrict__ bt, float* __restrict__ out)
{
    __shared__ __align__(16) unsigned short XT[16 * 264];   // 8448B
    __shared__ float red1[64], red2[64];
    const int t = threadIdx.x;
    const int id = blockIdx.x;
    const int b = id & 63, pt = id >> 6;                    // pt 0..63
    const int w = t >> 6, quad = (t >> 4) & 3, lane16 = t & 15;
    // ---- pack 16 rows of xf -> bf16 LDS ----
    {
        const int p = t >> 4, q = t & 15;
        const float* Xr = xf + ((long)(b * 1024 + pt * 16 + p)) * 256 + q * 16;
        float4 v0 = *(const float4*)(Xr + 0);
        float4 v1 = *(const float4*)(Xr + 4);
        float4 v2 = *(const float4*)(Xr + 8);
        float4 v3 = *(const float4*)(Xr + 12);
        uint4 pk0;
        pk0.x = bfpack2(v0.x, v0.y); pk0.y = bfpack2(v0.z, v0.w);
        pk0.z = bfpack2(v1.x, v1.y); pk0.w = bfpack2(v1.z, v1.w);
        uint4 pk1;
        pk1.x = bfpack2(v2.x, v2.y); pk1.y = bfpack2(v2.z, v2.w);
        pk1.z = bfpack2(v3.x, v3.y); pk1.w = bfpack2(v3.z, v3.w);
        *(uint4*)&XT[p * 264 + q * 16]     = pk0;
        *(uint4*)&XT[p * 264 + q * 16 + 8] = pk1;
    }
    __syncthreads();
    // ---- MFMA: 16 rows x 64 cols per wave ----
    f32x4 acc[4] = {{0.f,0.f,0.f,0.f},{0.f,0.f,0.f,0.f},{0.f,0.f,0.f,0.f},{0.f,0.f,0.f,0.f}};
    const unsigned short* Mb = MT + (long)b * 65536 + quad * 8;
    short8 bf4[4];
#pragma unroll
    for (int ni = 0; ni < 4; ++ni)
        bf4[ni] = *(const short8*)(Mb + (long)(w * 64 + ni * 16 + lane16) * 256);
#pragma unroll
    for (int ks = 0; ks < 8; ++ks) {
        short8 nbf[4];
        if (ks + 1 < 8) {
#pragma unroll
            for (int ni = 0; ni < 4; ++ni)
                nbf[ni] = *(const short8*)(Mb + (long)(w * 64 + ni * 16 + lane16) * 256 + (ks + 1) * 32);
        }
        short8 af = *(const short8*)&XT[lane16 * 264 + ks * 32 + quad * 8];
#pragma unroll
        for (int ni = 0; ni < 4; ++ni)
            acc[ni] = __builtin_amdgcn_mfma_f32_16x16x32_bf16(af, bf4[ni], acc[ni], 0, 0, 0);
#pragma unroll
        for (int ni = 0; ni < 4; ++ni) bf4[ni] = nbf[ni];
    }
    // ---- svec add + per-row stats (shuffle) ----
    float sv4[4];
#pragma unroll
    for (int ni = 0; ni < 4; ++ni) sv4[ni] = svec[b * 256 + w * 64 + ni * 16 + lane16];
#pragma unroll
    for (int r = 0; r < 4; ++r) {
        float s1 = 0.f, s2 = 0.f;
#pragma unroll
        for (int ni = 0; ni < 4; ++ni) {
            float v2 = acc[ni][r] + sv4[ni];
            acc[ni][r] = v2;
            s1 += v2; s2 += v2 * v2;
        }
#pragma unroll
        for (int m = 1; m <= 8; m <<= 1) {
            s1 += __shfl_xor(s1, m);
            s2 += __shfl_xor(s2, m);
        }
        if (lane16 == 0) {
            red1[(quad * 4 + r) * 4 + w] = s1;
            red2[(quad * 4 + r) * 4 + w] = s2;
        }
    }
    __syncthreads();
    // ---- LN + relu + residual, direct stores ----
#pragma unroll
    for (int r = 0; r < 4; ++r) {
        const int row = quad * 4 + r;
        float sa = red1[row * 4] + red1[row * 4 + 1] + red1[row * 4 + 2] + red1[row * 4 + 3];
        float sb = red2[row * 4] + red2[row * 4 + 1] + red2[row * 4 + 2] + red2[row * 4 + 3];
        float m = sa * (1.f / 256.f);
        float rr = rsqrtf(sb * (1.f / 256.f) - m * m + EPSV);
        const long grow = ((long)(b * 1024 + pt * 16 + row)) * 256;
#pragma unroll
        for (int ni = 0; ni < 4; ++ni) {
            const int col = w * 64 + ni * 16 + lane16;
            float a = acc[ni][r];
            float o = xf[grow + col] + fmaxf((a - m) * rr * g[col] + bt[col], 0.f);
            out[grow + col] = o;
        }
    }
}

extern "C" void kernel_launch(void* const* d_in, const int* in_sizes, int n_in,
                              void* d_out, int out_size, void* d_ws, size_t ws_size,
                              hipStream_t stream)
{
    (void)in_sizes; (void)n_in; (void)out_size; (void)ws_size;
    const float* x_feat = (const float*)d_in[0];
    const float* z_feat = (const float*)d_in[1];
    const float* Wz     = (const float*)d_in[2];
    const float* bz     = (const float*)d_in[3];
    const float* Wx     = (const float*)d_in[4];
    const float* bx     = (const float*)d_in[5];
    const float* Wdyn   = (const float*)d_in[6];
    const float* bdyn   = (const float*)d_in[7];
    const float* g_norm = (const float*)d_in[8];
    const float* b_norm = (const float*)d_in[9];
    const float* Wp     = (const float*)d_in[10];
    const float* bp     = (const float*)d_in[11];
    const float* g_ln   = (const float*)d_in[12];
    const float* b_ln   = (const float*)d_in[13];
    float* out = (float*)d_out;

    float* ws       = (float*)d_ws;
    float* point    = ws;                    // 1,048,576 f32
    float* dypart   = point + 1048576;       // 1,114,112
    float* partials = dypart + 1114112;      //    49,152
    float* csx      = partials + 49152;      //    16,384
    float* csz      = csx + 16384;           //    16,384
    float* svec     = csz + 16384;           //    16,384
    unsigned short* Gx = (unsigned short*)(svec + 16384);  // 4,194,304 ush
    unsigned short* Gz = Gx + 4194304;                     // 4,194,304
    unsigned short* MT = Gz + 4194304;                     // 4,194,304

    gram<<<384, 512, 0, stream>>>(x_feat, z_feat, Gx, Gz, csx, csz);
    projz<<<256, 256, 0, stream>>>(Gz, csz, Wz, bz, Wdyn, dypart);
    dpx<<<dim3(4, 64), 256, 0, stream>>>(Gx, csx, Wx, bx, dypart, bdyn,
                                         g_norm, Wp, point, partials);
    lnbuild<<<256, 256, 0, stream>>>(partials, point, g_norm, b_norm, Wp, bp,
                                     Wx, bx, MT, svec);
    final3<<<4096, 256, 0, stream>>>(x_feat, MT, svec, g_ln, b_ln, out);
}